// Round 3
// baseline (337.763 us; speedup 1.0000x reference)
//
#include <hip/hip_runtime.h>
#include <hip/hip_bf16.h>
#include <stdint.h>

// ---------- types / helpers ----------
typedef float  f32x4  __attribute__((ext_vector_type(4)));
typedef short  bf16x8 __attribute__((ext_vector_type(8)));
typedef short  bf16x4 __attribute__((ext_vector_type(4)));

#define MFMA16(A,B,C) __builtin_amdgcn_mfma_f32_16x16x32_bf16(A,B,C,0,0,0)

__device__ __forceinline__ short f2bf(float x){
    union { float f; uint32_t u; } v; v.f = x;
    uint32_t r = v.u + 0x7fffu + ((v.u >> 16) & 1u);   // RNE
    return (short)(r >> 16);
}
__device__ __forceinline__ float bf2f(short x){
    union { uint32_t u; float f; } v; v.u = ((uint32_t)(uint16_t)x) << 16;
    return v.f;
}
__device__ __forceinline__ bf16x8 pack8(f32x4 a, f32x4 b){
    bf16x8 r;
    r[0]=f2bf(a[0]); r[1]=f2bf(a[1]); r[2]=f2bf(a[2]); r[3]=f2bf(a[3]);
    r[4]=f2bf(b[0]); r[5]=f2bf(b[1]); r[6]=f2bf(b[2]); r[7]=f2bf(b[3]);
    return r;
}

// ---------- K0a: transpose Wq/Wk/Wv (fp32 [k][o]) -> WT bf16 [w][o][k] ----------
__global__ void k_prep_wt(const float* __restrict__ Wq, const float* __restrict__ Wk,
                          const float* __restrict__ Wv, short* __restrict__ WT){
    int blk = blockIdx.x;            // 192 = 3 * 64 tiles
    int w  = blk >> 6;
    int t  = blk & 63;
    int k0 = (t >> 3) << 6;
    int o0 = (t & 7) << 6;
    const float* W = (w == 0) ? Wq : ((w == 1) ? Wk : Wv);
    __shared__ float tile[64][65];
    int tx = threadIdx.x & 63, ty = threadIdx.x >> 6;    // ty 0..3
    #pragma unroll
    for (int i = 0; i < 64; i += 4)
        tile[ty + i][tx] = W[(size_t)(k0 + ty + i) * 512 + o0 + tx];
    __syncthreads();
    short* out = WT + (size_t)w * 512 * 512;
    #pragma unroll
    for (int i = 0; i < 64; i += 4)
        out[(size_t)(o0 + ty + i) * 512 + k0 + tx] = f2bf(tile[tx][ty + i]);
}

// ---------- K0b: WcatT bf16 [16ch][32c] (ch<8: We, ch>=8: Wg), bcat f32[16] ----------
__global__ void k_prep_wcat(const float* __restrict__ We, const float* __restrict__ Wg,
                            const float* __restrict__ be, const float* __restrict__ bg,
                            short* __restrict__ WcatT, float* __restrict__ bcat){
    int t = threadIdx.x;             // 512 threads
    int ch = t >> 5, c = t & 31;
    float v = (ch < 8) ? We[c * 8 + ch] : Wg[c * 8 + (ch - 8)];
    WcatT[ch * 32 + c] = f2bf(v);
    if (t < 16) bcat[t] = (t < 8) ? be[t] : bg[t - 8];
}

// ---------- K0c: nodes fp32 -> bf16 ----------
__global__ void k_prep_nodes(const float* __restrict__ nodes, short* __restrict__ nb){
    size_t i = ((size_t)blockIdx.x * 256 + threadIdx.x) * 8;
    f32x4 a = *(const f32x4*)(nodes + i);
    f32x4 b = *(const f32x4*)(nodes + i + 4);
    *(bf16x8*)(nb + i) = pack8(a, b);
}

// ---------- K1: QKV projections ----------
// q,k -> [b][h][l][64] bf16 ; v -> [b][h][64][m] bf16 (transposed)
__global__ void k_qkv(const short* __restrict__ nodesbf, const short* __restrict__ WT,
                      const float* __restrict__ bq, const float* __restrict__ bk,
                      const float* __restrict__ bv,
                      short* __restrict__ qb, short* __restrict__ kb, short* __restrict__ vTb){
    int bx = blockIdx.x;             // 1536
    int lt = bx & 255;
    int ob = bx >> 8;                // 0..5
    int wave = threadIdx.x >> 6, lane = threadIdx.x & 63;
    int lr = lane & 15, lg = lane >> 4;
    int row0 = lt << 4;
    int og = ob * 256 + wave * 64;
    int w  = og >> 9;                // 0=q,1=k,2=v
    int oo = og & 511;

    const short* Wp = WT + (size_t)w * 512 * 512;
    f32x4 acc[4] = {};
    const short* arow = nodesbf + (size_t)(row0 + lr) * 512 + lg * 8;
    #pragma unroll
    for (int kk = 0; kk < 16; ++kk){
        bf16x8 af = *(const bf16x8*)(arow + kk * 32);
        #pragma unroll
        for (int s = 0; s < 4; ++s){
            const short* bp = Wp + (size_t)(oo + s * 16 + lr) * 512 + kk * 32 + lg * 8;
            bf16x8 bfv = *(const bf16x8*)bp;
            acc[s] = MFMA16(af, bfv, acc[s]);
        }
    }
    const float* bias = (w == 0) ? bq : ((w == 1) ? bk : bv);
    int b  = row0 >> 10;
    int lb = (row0 & 1023) + lg * 4;
    #pragma unroll
    for (int s = 0; s < 4; ++s){
        int o = oo + s * 16 + lr;
        float bsv = bias[o];
        int h = o & 7, d = o >> 3;
        #pragma unroll
        for (int r = 0; r < 4; ++r){
            float v = acc[s][r] + bsv;
            short sv = f2bf(v);
            int l = lb + r;
            if (w == 0)       qb [((size_t)(b * 8 + h) * 1024 + l) * 64 + d] = sv;
            else if (w == 1)  kb [((size_t)(b * 8 + h) * 1024 + l) * 64 + d] = sv;
            else              vTb[((size_t)(b * 8 + h) * 64 + d) * 1024 + l] = sv;
        }
    }
}

// ---------- K2: FUSED scores + H + softmax + gated PV ----------
// grid 256 = b(4) x ltile(64), block 512 = 8 waves.
// Per iter (128 m): wave w owns m-slice w*16; qk MFMA (orig orientation:
// col=m=lr, row=l=4lg+r), e/g MFMA, exp/sigmoid epilogue -> H store +
// gated P into swizzled LDS. One barrier, then wave w = head w does PV MFMA.
// Denominator: per-lane fp32 accumulation (no shuffles in loop).
__global__ __launch_bounds__(512, 2) void k_main(
        const float* __restrict__ edges, const short* __restrict__ qb,
        const short* __restrict__ kb, const short* __restrict__ vTb,
        const short* __restrict__ WcatT, const float* __restrict__ bcat,
        float* __restrict__ Hout, float* __restrict__ attn){
    // XCD-aware swizzle: XCD j gets only blocks of b = j>>1 (k/v stay L2-hot)
    int hw = blockIdx.x;
    int j  = hw & 7, kk0 = hw >> 3;
    int b  = j >> 1;
    int lt = ((j & 1) << 5) | kk0;
    int l0 = lt << 4;

    int w    = threadIdx.x >> 6;
    int lane = threadIdx.x & 63;
    int lr = lane & 15, lg = lane >> 4;

    __shared__ short eg[8][4][16][20];      // [wave][l>>2][m][16ch+4pad]
    __shared__ short Plds[2][8 * 16 * 128]; // dbuf, swizzled [h][l][m]
    __shared__ float den[8][8][16];         // [wave-partial][h][l]
    __shared__ float Os[16][516];

    bf16x8 wf = *(const bf16x8*)(WcatT + lr * 32 + lg * 8);
    f32x4  bc = *(const f32x4*)(bcat + lg * 4);
    const size_t bl0 = (size_t)(b * 1024 + l0);

    f32x4 O[4] = {};
    float dsum[8][4] = {};
    f32x4 zero = {0.f, 0.f, 0.f, 0.f};

    for (int iter = 0; iter < 8; ++iter){
        const int m0 = iter * 128 + w * 16;
        // ---- qk: S[h], col=m=lr, row=l=4lg+r ----
        f32x4 S[8] = {};
        #pragma unroll
        for (int h = 0; h < 8; ++h){
            #pragma unroll
            for (int half = 0; half < 2; ++half){
                bf16x8 qf = *(const bf16x8*)(qb + ((size_t)(b * 8 + h) * 1024 + l0 + lr) * 64 + half * 32 + lg * 8);
                bf16x8 kf = *(const bf16x8*)(kb + ((size_t)(b * 8 + h) * 1024 + m0 + lr) * 64 + half * 32 + lg * 8);
                S[h] = MFMA16(qf, kf, S[h]);
            }
        }

        // ---- e/g + epilogue, 4 row-chunks, 1-chunk-ahead edge pipeline ----
        f32x4 ebuf[2][8];
        #pragma unroll
        for (int s = 0; s < 4; ++s){   // prologue: chunk r=0 (l = 4s+0)
            const float* ep = edges + ((bl0 + 4 * s) * 1024 + m0 + lr) * 32 + lg * 8;
            ebuf[0][2 * s]     = *(const f32x4*)ep;
            ebuf[0][2 * s + 1] = *(const f32x4*)(ep + 4);
        }
        short* Pcur = &Plds[iter & 1][0];
        #pragma unroll
        for (int r = 0; r < 4; ++r){
            if (r < 3){                // prefetch chunk r+1 (l = 4s+r+1)
                #pragma unroll
                for (int s = 0; s < 4; ++s){
                    const float* ep = edges + ((bl0 + 4 * s + r + 1) * 1024 + m0 + lr) * 32 + lg * 8;
                    ebuf[(r + 1) & 1][2 * s]     = *(const f32x4*)ep;
                    ebuf[(r + 1) & 1][2 * s + 1] = *(const f32x4*)(ep + 4);
                }
            }
            // e/g MFMA for l in {r, 4+r, 8+r, 12+r}: D[ch][m], col=m=lr, row=ch=4lg+rr
            #pragma unroll
            for (int s = 0; s < 4; ++s){
                f32x4 d = MFMA16(wf, pack8(ebuf[r & 1][2 * s], ebuf[r & 1][2 * s + 1]), zero);
                bf16x4 dv;
                #pragma unroll
                for (int rr = 0; rr < 4; ++rr) dv[rr] = f2bf(d[rr] + bc[rr]);
                *(bf16x4*)&eg[w][s][lr][lg * 4] = dv;
            }
            // epilogue row-set r: lane -> (l = 4lg+r, m = m0+lr)
            int l = 4 * lg + r;
            bf16x8 e8 = *(const bf16x8*)&eg[w][lg][lr][0];
            bf16x8 g8 = *(const bf16x8*)&eg[w][lg][lr][8];
            float Hv[8]; short pv[8];
            #pragma unroll
            for (int h = 0; h < 8; ++h){
                float s = S[h][r] * 0.125f;
                s = fminf(fmaxf(s, -5.f), 5.f);
                float hv = s + bf2f(e8[h]);
                Hv[h] = hv;
                float ex = __expf(hv);
                dsum[h][r] += ex;
                float sg = __builtin_amdgcn_rcpf(1.f + __expf(-bf2f(g8[h])));
                pv[h] = f2bf(ex * sg);
            }
            size_t idx = ((bl0 + l) * 1024 + m0 + lr) * 8;
            f32x4 h0 = {Hv[0], Hv[1], Hv[2], Hv[3]};
            f32x4 h1 = {Hv[4], Hv[5], Hv[6], Hv[7]};
            *(f32x4*)(Hout + idx)     = h0;
            *(f32x4*)(Hout + idx + 4) = h1;
            #pragma unroll
            for (int h = 0; h < 8; ++h){
                int byte = ((h * 16 + l) << 8) + ((w * 16 + lr) << 1);
                *(short*)((char*)Pcur + (byte ^ ((l & 7) << 4))) = pv[h];
            }
        }
        __syncthreads();               // P_lds[iter&1] complete (dbuf: 1 barrier/iter)

        // ---- PV: wave w = head w; B = P (col=l=lr, k=m), A = vT (row=d) ----
        const short* vbase = vTb + (size_t)(b * 8 + w) * 64 * 1024 + iter * 128;
        #pragma unroll
        for (int ks = 0; ks < 4; ++ks){
            int mm = ks * 32 + lg * 8;
            int byte = ((w * 16 + lr) << 8) + (mm << 1);
            bf16x8 pf = *(const bf16x8*)((char*)Pcur + (byte ^ ((lr & 7) << 4)));
            #pragma unroll
            for (int dt = 0; dt < 4; ++dt){
                bf16x8 vf = *(const bf16x8*)(vbase + (size_t)(dt * 16 + lr) * 1024 + mm);
                O[dt] = MFMA16(vf, pf, O[dt]);
            }
        }
    }

    // ---- denominator: reduce per-lane partials over lr, then cross-wave ----
    #pragma unroll
    for (int h = 0; h < 8; ++h){
        #pragma unroll
        for (int r = 0; r < 4; ++r){
            float t = dsum[h][r];
            t += __shfl_xor(t, 1);
            t += __shfl_xor(t, 2);
            t += __shfl_xor(t, 4);
            t += __shfl_xor(t, 8);
            if (lr == 0) den[w][h][4 * lg + r] = t;
        }
    }
    __syncthreads();
    float ds = 0.f;
    #pragma unroll
    for (int w2 = 0; w2 < 8; ++w2) ds += den[w2][w][lr];
    float inv = __builtin_amdgcn_rcpf(ds);

    // ---- normalize + staged coalesced attn write ----
    #pragma unroll
    for (int dt = 0; dt < 4; ++dt){
        #pragma unroll
        for (int r = 0; r < 4; ++r)
            Os[lr][(dt * 16 + 4 * lg + r) * 8 + w] = O[dt][r] * inv;   // col = d*8 + h
    }
    __syncthreads();
    {
        int row = threadIdx.x >> 5;            // 0..15
        int c0  = (threadIdx.x & 31) * 4;
        float* dst = attn + (bl0 + row) * 512 + c0;
        #pragma unroll
        for (int jj = 0; jj < 4; ++jj)
            *(f32x4*)(dst + jj * 128) = *(const f32x4*)&Os[row][c0 + jj * 128];
    }
}

// ---------- workspace layout ----------
#define OFF_WT    ((size_t)0x0000000)   // 1.5 MB
#define OFF_WCAT  ((size_t)0x0180000)   // 1 KB
#define OFF_BCAT  ((size_t)0x0180400)   // 64 B
#define OFF_NB    ((size_t)0x0200000)   // 4 MB (nodes bf16)
#define OFF_Q     ((size_t)0x0600000)   // 4 MB
#define OFF_K     ((size_t)0x0A00000)   // 4 MB
#define OFF_VT    ((size_t)0x0E00000)   // 4 MB -> total ~18 MB

extern "C" void kernel_launch(void* const* d_in, const int* in_sizes, int n_in,
                              void* d_out, int out_size, void* d_ws, size_t ws_size,
                              hipStream_t stream) {
    const float* nodes = (const float*)d_in[0];
    const float* edges = (const float*)d_in[1];
    const float* Wq = (const float*)d_in[2];
    const float* bq = (const float*)d_in[3];
    const float* Wk = (const float*)d_in[4];
    const float* bk = (const float*)d_in[5];
    const float* Wv = (const float*)d_in[6];
    const float* bv = (const float*)d_in[7];
    const float* Wg = (const float*)d_in[8];
    const float* bg = (const float*)d_in[9];
    const float* We = (const float*)d_in[10];
    const float* be = (const float*)d_in[11];

    float* out_attn = (float*)d_out;
    float* out_H    = out_attn + (size_t)4 * 1024 * 512;

    char* ws = (char*)d_ws;
    short* WT    = (short*)(ws + OFF_WT);
    short* WcatT = (short*)(ws + OFF_WCAT);
    float* bcat  = (float*)(ws + OFF_BCAT);
    short* nb    = (short*)(ws + OFF_NB);
    short* qb    = (short*)(ws + OFF_Q);
    short* kb    = (short*)(ws + OFF_K);
    short* vTb   = (short*)(ws + OFF_VT);

    k_prep_wt   <<<192, 256, 0, stream>>>(Wq, Wk, Wv, WT);
    k_prep_wcat <<<1, 512, 0, stream>>>(We, Wg, be, bg, WcatT, bcat);
    k_prep_nodes<<<1024, 256, 0, stream>>>(nodes, nb);
    k_qkv       <<<1536, 256, 0, stream>>>(nb, WT, bq, bk, bv, qb, kb, vTb);
    k_main      <<<256, 512, 0, stream>>>(edges, qb, kb, vTb, WcatT, bcat, out_H, out_attn);
}

// Round 5
// 293.755 us; speedup vs baseline: 1.1498x; 1.1498x over previous
//
#include <hip/hip_runtime.h>
#include <hip/hip_bf16.h>
#include <stdint.h>

// ---------- types / helpers ----------
typedef float  f32x4  __attribute__((ext_vector_type(4)));
typedef float  f32x2  __attribute__((ext_vector_type(2)));
typedef short  bf16x8 __attribute__((ext_vector_type(8)));
typedef short  bf16x4 __attribute__((ext_vector_type(4)));

#define MFMA16(A,B,C) __builtin_amdgcn_mfma_f32_16x16x32_bf16(A,B,C,0,0,0)

__device__ __forceinline__ short f2bf(float x){
    union { float f; uint32_t u; } v; v.f = x;
    uint32_t r = v.u + 0x7fffu + ((v.u >> 16) & 1u);   // RNE
    return (short)(r >> 16);
}
__device__ __forceinline__ float bf2f(short x){
    union { uint32_t u; float f; } v; v.u = ((uint32_t)(uint16_t)x) << 16;
    return v.f;
}
__device__ __forceinline__ bf16x8 pack8(f32x4 a, f32x4 b){
    bf16x8 r;
    r[0]=f2bf(a[0]); r[1]=f2bf(a[1]); r[2]=f2bf(a[2]); r[3]=f2bf(a[3]);
    r[4]=f2bf(b[0]); r[5]=f2bf(b[1]); r[6]=f2bf(b[2]); r[7]=f2bf(b[3]);
    return r;
}

// ---------- K0a: transpose Wq/Wk/Wv (fp32 [k][o]) -> WT bf16 [w][o][k] ----------
__global__ void k_prep_wt(const float* __restrict__ Wq, const float* __restrict__ Wk,
                          const float* __restrict__ Wv, short* __restrict__ WT){
    int blk = blockIdx.x;            // 192 = 3 * 64 tiles
    int w  = blk >> 6;
    int t  = blk & 63;
    int k0 = (t >> 3) << 6;
    int o0 = (t & 7) << 6;
    const float* W = (w == 0) ? Wq : ((w == 1) ? Wk : Wv);
    __shared__ float tile[64][65];
    int tx = threadIdx.x & 63, ty = threadIdx.x >> 6;    // ty 0..3
    #pragma unroll
    for (int i = 0; i < 64; i += 4)
        tile[ty + i][tx] = W[(size_t)(k0 + ty + i) * 512 + o0 + tx];
    __syncthreads();
    short* out = WT + (size_t)w * 512 * 512;
    #pragma unroll
    for (int i = 0; i < 64; i += 4)
        out[(size_t)(o0 + ty + i) * 512 + k0 + tx] = f2bf(tile[tx][ty + i]);
}

// ---------- K0b: WcatT bf16 [16ch][32c] (ch<8: We, ch>=8: Wg), bcat f32[16] ----------
__global__ void k_prep_wcat(const float* __restrict__ We, const float* __restrict__ Wg,
                            const float* __restrict__ be, const float* __restrict__ bg,
                            short* __restrict__ WcatT, float* __restrict__ bcat){
    int t = threadIdx.x;             // 512 threads
    int ch = t >> 5, c = t & 31;
    float v = (ch < 8) ? We[c * 8 + ch] : Wg[c * 8 + (ch - 8)];
    WcatT[ch * 32 + c] = f2bf(v);
    if (t < 16) bcat[t] = (t < 8) ? be[t] : bg[t - 8];
}

// ---------- K0c: nodes fp32 -> bf16 ----------
__global__ void k_prep_nodes(const float* __restrict__ nodes, short* __restrict__ nb){
    size_t i = ((size_t)blockIdx.x * 256 + threadIdx.x) * 8;
    f32x4 a = *(const f32x4*)(nodes + i);
    f32x4 b = *(const f32x4*)(nodes + i + 4);
    *(bf16x8*)(nb + i) = pack8(a, b);
}

// ---------- K1: QKV projections (sector-dense staged stores) ----------
// q,k -> [b][h][l][64] bf16 ; v -> [b][h][64][m] bf16
__global__ void k_qkv(const short* __restrict__ nodesbf, const short* __restrict__ WT,
                      const float* __restrict__ bq, const float* __restrict__ bk,
                      const float* __restrict__ bv,
                      short* __restrict__ qb, short* __restrict__ kb, short* __restrict__ vTb){
    int bx = blockIdx.x;             // 1536
    int lt = bx & 255;
    int ob = bx >> 8;                // 0..5
    int wave = threadIdx.x >> 6, lane = threadIdx.x & 63;
    int lr = lane & 15, lg = lane >> 4;
    int row0 = lt << 4;
    int og = ob * 256 + wave * 64;
    int w  = og >> 9;                // 0=q,1=k,2=v
    int oo = og & 511;
    int dhalf = ob & 1;              // which 32-wide d half this block owns

    const short* Wp = WT + (size_t)w * 512 * 512;
    f32x4 acc[4] = {};
    const short* arow = nodesbf + (size_t)(row0 + lr) * 512 + lg * 8;
    #pragma unroll
    for (int kk = 0; kk < 16; ++kk){
        bf16x8 af = *(const bf16x8*)(arow + kk * 32);
        #pragma unroll
        for (int s = 0; s < 4; ++s){
            const short* bp = Wp + (size_t)(oo + s * 16 + lr) * 512 + kk * 32 + lg * 8;
            bf16x8 bfv = *(const bf16x8*)bp;
            acc[s] = MFMA16(af, bfv, acc[s]);
        }
    }
    const float* bias = (w == 0) ? bq : ((w == 1) ? bk : bv);
    int b  = row0 >> 10;
    int lbase = row0 & 1023;

    __shared__ short St[4096];       // q/k: [l16][h8][dd32]  v: [h8][dd32][m16]
    #pragma unroll
    for (int s = 0; s < 4; ++s){
        int o = oo + s * 16 + lr;
        float bsv = bias[o];
        int h = o & 7, dd = (o >> 3) & 31;
        #pragma unroll
        for (int r = 0; r < 4; ++r){
            short sv = f2bf(acc[s][r] + bsv);
            int l = lg * 4 + r;
            if (w < 2) St[(l << 8) + (h << 5) + dd] = sv;
            else       St[(h << 9) + (dd << 4) + l] = sv;
        }
    }
    __syncthreads();
    int t = threadIdx.x;
    bf16x8 v0 = *(const bf16x8*)&St[t * 16];
    bf16x8 v1 = *(const bf16x8*)&St[t * 16 + 8];
    if (w < 2){
        short* dst = (w == 0) ? qb : kb;
        int l = t >> 4, h = (t >> 1) & 7, dd0 = (t & 1) << 4;
        size_t a = ((size_t)(b * 8 + h) * 1024 + lbase + l) * 64 + dhalf * 32 + dd0;
        *(bf16x8*)(dst + a)     = v0;
        *(bf16x8*)(dst + a + 8) = v1;
    } else {
        int h = t >> 5, dd = t & 31;
        size_t a = ((size_t)(b * 8 + h) * 64 + dhalf * 32 + dd) * 1024 + lbase;
        *(bf16x8*)(vTb + a)     = v0;
        *(bf16x8*)(vTb + a + 8) = v1;
    }
}

// ---------- K2a: scores/H/exp/sigmoid, ALL stores sector-dense ----------
// grid 4096 = b(4) x lt(64) x mt(16), XCD-swizzled; block 256 = 4 waves, wave = m-16.
// H: staged in LDS per r-pass, written as dense dwordx4 runs.
// P (bf16): tile-major [b][h][lt64][T64][l16][m16], T = mt*4+w; dense 512B tiles.
// psum (f32): [b][lt][mt][w][h8][l16]; dense 512B per wave.
__global__ __launch_bounds__(256, 4) void k_hsg(
        const float* __restrict__ edges, const short* __restrict__ qb,
        const short* __restrict__ kb, const short* __restrict__ WcatT,
        const float* __restrict__ bcat,
        float* __restrict__ Hout, short* __restrict__ Pb,
        float* __restrict__ psum){
    int bx = blockIdx.x;
    int j  = bx & 7;  int b = j >> 1;          // XCD j sees a single batch b
    int rest = bx >> 3;
    int mt = rest & 15;
    int lt = (rest >> 4) | ((j & 1) << 5);
    int w = threadIdx.x >> 6, lane = threadIdx.x & 63;
    int lr = lane & 15, lg = lane >> 4;
    int l0 = lt << 4;
    int mg = (mt << 6) + (w << 4);
    const size_t bl0 = (size_t)(b * 1024 + l0);

    __shared__ short eg[4][4][16][24];   // [w][s][m][16ch+pad]
    __shared__ float Hst[4][512];        // [w][2KB H bounce]
    __shared__ short Ps[4][2048];        // [w][h8][l16][m16]
    __shared__ float den[4][128];        // [w][h8][l16]

    // ---- qk: S[h], col=m=lr, row=l=4lg+r ----
    f32x4 S[8] = {};
    #pragma unroll
    for (int h = 0; h < 8; ++h){
        #pragma unroll
        for (int half = 0; half < 2; ++half){
            bf16x8 qf = *(const bf16x8*)(qb + ((size_t)(b * 8 + h) * 1024 + l0 + lr) * 64 + half * 32 + lg * 8);
            bf16x8 kf = *(const bf16x8*)(kb + ((size_t)(b * 8 + h) * 1024 + mg + lr) * 64 + half * 32 + lg * 8);
            S[h] = MFMA16(qf, kf, S[h]);
        }
    }

    bf16x8 wf = *(const bf16x8*)(WcatT + lr * 32 + lg * 8);
    f32x4  bc = *(const f32x4*)(bcat + lg * 4);
    f32x4 zero = {0.f, 0.f, 0.f, 0.f};

    #pragma unroll
    for (int r = 0; r < 4; ++r){
        // e/g MFMA for l in {r, 4+r, 8+r, 12+r}
        #pragma unroll
        for (int s = 0; s < 4; ++s){
            int l = 4 * s + r;
            const float* ep = edges + ((bl0 + l) * 1024 + mg + lr) * 32 + lg * 8;
            f32x4 e0 = *(const f32x4*)ep;
            f32x4 e1 = *(const f32x4*)(ep + 4);
            f32x4 d = MFMA16(wf, pack8(e0, e1), zero);
            bf16x4 dv;
            #pragma unroll
            for (int rr = 0; rr < 4; ++rr) dv[rr] = f2bf(d[rr] + bc[rr]);
            *(bf16x4*)&eg[w][s][lr][lg * 4] = dv;
        }
        // epilogue: lane owns (l = 4lg+r, m = mg+lr), all 8 heads
        int l = 4 * lg + r;
        bf16x8 e8 = *(const bf16x8*)&eg[w][lg][lr][0];
        bf16x8 g8 = *(const bf16x8*)&eg[w][lg][lr][8];
        float Hv[8], ex[8];
        #pragma unroll
        for (int h = 0; h < 8; ++h){
            float s = S[h][r] * 0.125f;
            s = fminf(fmaxf(s, -5.f), 5.f);
            Hv[h] = s + bf2f(e8[h]);
            ex[h] = __expf(Hv[h]);
            float sg = __builtin_amdgcn_rcpf(1.f + __expf(-bf2f(g8[h])));
            Ps[w][(h << 8) + (l << 4) + lr] = f2bf(ex[h] * sg);
        }
        // denominator partials (per 16-m slice)
        #pragma unroll
        for (int h = 0; h < 8; ++h){
            float t = ex[h];
            t += __shfl_xor(t, 1);
            t += __shfl_xor(t, 2);
            t += __shfl_xor(t, 4);
            t += __shfl_xor(t, 8);
            if (lr == 0) den[w][(h << 4) + l] = t;
        }
        // H bounce: lane writes its 8 f32 at [lg*128 + lr*8]
        f32x4 h0 = {Hv[0], Hv[1], Hv[2], Hv[3]};
        f32x4 h1 = {Hv[4], Hv[5], Hv[6], Hv[7]};
        *(f32x4*)&Hst[w][lg * 128 + lr * 8]     = h0;
        *(f32x4*)&Hst[w][lg * 128 + lr * 8 + 4] = h1;
        // dense H write: 2 instrs, each fully covers 64-B sectors
        f32x4 o0 = *(const f32x4*)&Hst[w][lane * 4];
        f32x4 o1 = *(const f32x4*)&Hst[w][256 + lane * 4];
        int off = (lane * 4) & 127;
        *(f32x4*)(Hout + (bl0 + 4 * (lane >> 5) + r)       * 8192 + mg * 8 + off) = o0;
        *(f32x4*)(Hout + (bl0 + 4 * ((lane >> 5) + 2) + r) * 8192 + mg * 8 + off) = o1;
    }

    // ---- dense P write: wave's 4 KB tile-major region ----
    #pragma unroll
    for (int jj = 0; jj < 4; ++jj){
        int f = jj * 512 + lane * 8;     // shorts in Ps[w] (FIX: was jj*1024, OOB)
        int h = f >> 8;
        bf16x8 pv = *(const bf16x8*)&Ps[w][f];
        size_t a = (((size_t)(b * 8 + h) * 64 + lt) * 64 + (mt * 4 + w)) * 256 + (f & 255);
        *(bf16x8*)(Pb + a) = pv;
    }
    // ---- dense psum write: 512 B per wave ----
    {
        f32x2 dv = *(const f32x2*)&den[w][lane * 2];
        size_t a = (((size_t)(b * 64 + lt) * 16 + mt) * 4 + w) * 128 + lane * 2;
        *(f32x2*)(psum + a) = dv;
    }
}

// ---------- K2b: O = (P @ v) / rowsum — streaming MFMA over tile-major P ----------
// grid 256 = b x lt (XCD-swizzled); block 512 = 8 waves, wave = head
__global__ void k_pv(const short* __restrict__ Pb, const float* __restrict__ psum,
                     const short* __restrict__ vTb, float* __restrict__ attn){
    int bx = blockIdx.x;
    int j  = bx & 7;  int b = j >> 1;
    int lt = ((j & 1) << 5) | (bx >> 3);
    int h    = threadIdx.x >> 6;
    int lane = threadIdx.x & 63;
    int lr = lane & 15, lg = lane >> 4;
    int l0 = lt << 4;

    const short* Pbase = Pb  + (((size_t)(b * 8 + h) * 64 + lt) * 64) * 256;
    const short* vbase = vTb + (size_t)(b * 8 + h) * 65536;

    f32x4 O[4] = {};
    for (int ks = 0; ks < 32; ++ks){
        // B-frag: col=l=lr, k = m-local; tile T = ks*2 + (lg>>1)
        bf16x8 pf = *(const bf16x8*)(Pbase + (ks * 2 + (lg >> 1)) * 256 + lr * 16 + (lg & 1) * 8);
        #pragma unroll
        for (int dt = 0; dt < 4; ++dt){
            bf16x8 vf = *(const bf16x8*)(vbase + (size_t)(dt * 16 + lr) * 1024 + ks * 32 + lg * 8);
            O[dt] = MFMA16(vf, pf, O[dt]);
        }
    }

    // denominator: sum 64 partials per (h, l=lr)
    const float* pp = psum + ((size_t)(b * 64 + lt) * 16) * 512;
    float ds = 0.f;
    #pragma unroll
    for (int c = 0; c < 16; ++c)
        ds += pp[(c * 4 + lg) * 128 + h * 16 + lr];
    ds += __shfl_xor(ds, 16);
    ds += __shfl_xor(ds, 32);
    float inv = __builtin_amdgcn_rcpf(ds);

    // stage normalized O, block-coalesced dense write
    __shared__ float Os[16][516];
    #pragma unroll
    for (int dt = 0; dt < 4; ++dt){
        #pragma unroll
        for (int r = 0; r < 4; ++r)
            Os[lr][(dt * 16 + lg * 4 + r) * 8 + h] = O[dt][r] * inv;   // d = dt*16+4lg+r, l = lr
    }
    __syncthreads();
    int row = threadIdx.x >> 5;          // 0..15
    int cb  = (threadIdx.x & 31) * 16;   // 0..496
    float* dst = attn + ((size_t)(b * 1024 + l0 + row)) * 512 + cb;
    #pragma unroll
    for (int jj = 0; jj < 16; jj += 4)
        *(f32x4*)(dst + jj) = *(const f32x4*)&Os[row][cb + jj];
}

// ---------- workspace layout ----------
#define OFF_WT    ((size_t)0x0000000)   // 1.5 MB
#define OFF_WCAT  ((size_t)0x0180000)   // 1 KB
#define OFF_BCAT  ((size_t)0x0180400)   // 64 B
#define OFF_NB    ((size_t)0x0200000)   // 4 MB (nodes bf16)
#define OFF_Q     ((size_t)0x0600000)   // 4 MB
#define OFF_K     ((size_t)0x0A00000)   // 4 MB
#define OFF_VT    ((size_t)0x0E00000)   // 4 MB
#define OFF_P     ((size_t)0x1200000)   // 64 MB (P bf16 tile-major)
#define OFF_PS    ((size_t)0x5200000)   // 8.4 MB (psum f32) -> total ~95 MB

extern "C" void kernel_launch(void* const* d_in, const int* in_sizes, int n_in,
                              void* d_out, int out_size, void* d_ws, size_t ws_size,
                              hipStream_t stream) {
    const float* nodes = (const float*)d_in[0];
    const float* edges = (const float*)d_in[1];
    const float* Wq = (const float*)d_in[2];
    const float* bq = (const float*)d_in[3];
    const float* Wk = (const float*)d_in[4];
    const float* bk = (const float*)d_in[5];
    const float* Wv = (const float*)d_in[6];
    const float* bv = (const float*)d_in[7];
    const float* Wg = (const float*)d_in[8];
    const float* bg = (const float*)d_in[9];
    const float* We = (const float*)d_in[10];
    const float* be = (const float*)d_in[11];

    float* out_attn = (float*)d_out;
    float* out_H    = out_attn + (size_t)4 * 1024 * 512;

    char* ws = (char*)d_ws;
    short* WT    = (short*)(ws + OFF_WT);
    short* WcatT = (short*)(ws + OFF_WCAT);
    float* bcat  = (float*)(ws + OFF_BCAT);
    short* nb    = (short*)(ws + OFF_NB);
    short* qb    = (short*)(ws + OFF_Q);
    short* kb    = (short*)(ws + OFF_K);
    short* vTb   = (short*)(ws + OFF_VT);
    short* Pb    = (short*)(ws + OFF_P);
    float* psum  = (float*)(ws + OFF_PS);

    k_prep_wt   <<<192, 256, 0, stream>>>(Wq, Wk, Wv, WT);
    k_prep_wcat <<<1, 512, 0, stream>>>(We, Wg, be, bg, WcatT, bcat);
    k_prep_nodes<<<1024, 256, 0, stream>>>(nodes, nb);
    k_qkv       <<<1536, 256, 0, stream>>>(nb, WT, bq, bk, bv, qb, kb, vTb);
    k_hsg       <<<4096, 256, 0, stream>>>(edges, qb, kb, WcatT, bcat, out_H, Pb, psum);
    k_pv        <<<256, 512, 0, stream>>>(Pb, psum, vTb, out_attn);
}